// Round 3
// baseline (11.698 us; speedup 1.0000x reference)
//
#include <hip/hip_runtime.h>

// MI upper bound (CLUB, non-variational), algebraically reduced:
//   upper_bound = sum_d ( S2_d / N - (S1_d / N)^2 )
// where S1_d = sum_i y[i,d], S2_d = sum_i y[i,d]^2.
// N=2048, D=64, input f32 row-major [N, D] (512 KB).
//
// Single fused kernel (1 graph node). 32 producer blocks write per-column
// (S1,S2) partials + a release-published magic flag; block 0 relaxed-polls
// the 32 flags, issues one agent acquire fence, reduces, writes the scalar.
// Flags are reset to 0 by the consumer each call and producers overwrite
// partials before publishing -> deterministic and poison-robust replays.

#define NTHR 256
#define NBLK 32
#define FLAG_MAGIC 0x5AC0FFEE00DDBA11ULL

// ws layout (floats):
//   [0 .. NBLK*128)   per-block partials: 64 S1 columns then 64 S2 columns
//   float offset NBLK*128: unsigned long long flags[NBLK]

__global__ __launch_bounds__(NTHR)
void mi_fused(const float* __restrict__ y, float* __restrict__ ws,
              float* __restrict__ out) {
    __shared__ float4 l1[NTHR];   // 4 KB
    __shared__ float4 l2[NTHR];   // 4 KB
    __shared__ float  sm[NTHR];   // 1 KB
    unsigned long long* flags = (unsigned long long*)(ws + NBLK * 128);
    const int t = threadIdx.x;
    const int b = blockIdx.x;

    // ---- producer: 16 KB chunk = 1024 float4, 4 coalesced float4 loads/thread
    // float4 index f = t + 256k: column group = 4*(t&15) (invariant), rows disjoint.
    const float4* y4 = (const float4*)y + (size_t)b * 1024;
    float4 a1 = make_float4(0.f, 0.f, 0.f, 0.f);
    float4 a2 = make_float4(0.f, 0.f, 0.f, 0.f);
    #pragma unroll
    for (int k = 0; k < 4; ++k) {
        const float4 v = y4[t + NTHR * k];
        a1.x += v.x;     a1.y += v.y;     a1.z += v.z;     a1.w += v.w;
        a2.x += v.x*v.x; a2.y += v.y*v.y; a2.z += v.z*v.z; a2.w += v.w*v.w;
    }
    l1[t] = a1;
    l2[t] = a2;
    __syncthreads();

    // column c: sum element (c&3) of float4s at indices 16j + (c>>2), j=0..15.
    // Bank = c%32 across lanes -> 2-way aliasing only (free).
    if (t < 64) {
        const int g = t >> 2, e = t & 3;
        float s1 = 0.f, s2 = 0.f;
        #pragma unroll
        for (int j = 0; j < 16; ++j) {
            s1 += ((const float*)&l1[16 * j + g])[e];
            s2 += ((const float*)&l2[16 * j + g])[e];
        }
        ws[b * 128 + t]      = s1;
        ws[b * 128 + 64 + t] = s2;
    }
    // Release by lane 0 of the SAME wave that issued the partial stores.
    if (t == 0)
        __hip_atomic_store(&flags[b], FLAG_MAGIC, __ATOMIC_RELEASE,
                           __HIP_MEMORY_SCOPE_AGENT);

    if (b != 0) return;

    // ---- consumer: block 0 only. Relaxed poll, one acquire fence.
    if (t < NBLK) {
        while (__hip_atomic_load(&flags[t], __ATOMIC_RELAXED,
                                 __HIP_MEMORY_SCOPE_AGENT) != FLAG_MAGIC) {}
        // reset for the next (deterministic) replay
        __hip_atomic_store(&flags[t], 0ULL, __ATOMIC_RELAXED,
                           __HIP_MEMORY_SCOPE_AGENT);
    }
    __syncthreads();
    __builtin_amdgcn_fence(__ATOMIC_ACQUIRE, "agent");

    // 4096 partial floats; thread t sums half h=(t>>6)&1, col c=t&63 over
    // 16 blocks of parity t>>7 (agent-scope loads bypass stale caches).
    float p = 0.f;
    #pragma unroll
    for (int k = 0; k < 16; ++k)
        p += __hip_atomic_load(&ws[t + NTHR * k], __ATOMIC_RELAXED,
                               __HIP_MEMORY_SCOPE_AGENT);
    sm[t] = p;
    __syncthreads();
    if (t < 128) sm[t] = sm[t] + sm[t + 128];   // combine block parities
    __syncthreads();
    if (t < 64) {
        const float invN = 1.0f / 2048.0f;
        const float S1 = sm[t];        // h=0
        const float S2 = sm[t + 64];   // h=1
        float v = S2 * invN - (S1 * invN) * (S1 * invN);
        #pragma unroll
        for (int off = 32; off > 0; off >>= 1)
            v += __shfl_down(v, off);
        if (t == 0) out[0] = v;
    }
}

extern "C" void kernel_launch(void* const* d_in, const int* in_sizes, int n_in,
                              void* d_out, int out_size, void* d_ws, size_t ws_size,
                              hipStream_t stream) {
    const float* y = (const float*)d_in[0];
    float* out = (float*)d_out;
    float* ws  = (float*)d_ws;   // needs NBLK*128*4 + NBLK*8 = 16640 B

    mi_fused<<<NBLK, NTHR, 0, stream>>>(y, ws, out);
}

// Round 4
// 9.530 us; speedup vs baseline: 1.2275x; 1.2275x over previous
//
#include <hip/hip_runtime.h>

// MI upper bound (CLUB, non-variational), algebraically reduced:
//   upper_bound = sum_d ( S2_d / N - (S1_d / N)^2 )
// where S1_d = sum_i y[i,d], S2_d = sum_i y[i,d]^2.
// N=2048, D=64, input f32 row-major [N, D] (512 KB).
//
// Round-1 structure (measured 9.49 us) + ONE change: dedicated consumer.
// Grid = 65 blocks: blocks 1..64 produce per-column (S1,S2) partials and
// release-publish a magic flag; block 0 starts polling immediately at
// dispatch (overlapping producers), then acquires, reduces, writes out.
// Flags reset to 0 by the consumer each call; producers fully overwrite
// their partials before publishing -> deterministic, poison-robust replays.

#define N_ROWS 2048
#define D_COLS 64
#define NPROD 64
#define NTHR 256
#define ROWS_PER_BLOCK (N_ROWS / NPROD)   // 32
#define FLAG_MAGIC 0x5AC0FFEE00DDBA11ULL

// ws layout (floats):
//   [0 .. NPROD*128)  per-producer partials: 64 S1 columns then 64 S2 columns
//   float offset NPROD*128: unsigned long long flags[NPROD]

__global__ __launch_bounds__(NTHR)
void mi_fused(const float* __restrict__ y, float* __restrict__ ws,
              float* __restrict__ out) {
    __shared__ float s1s[NTHR];
    __shared__ float s2s[NTHR];
    unsigned long long* flags = (unsigned long long*)(ws + NPROD * 128);
    const int t = threadIdx.x;
    const int b = blockIdx.x;

    if (b != 0) {
        // ---- producer (blocks 1..64): same as round-1 kernel ----
        const int chunk = b - 1;
        const int col  = t & 63;
        const int rsub = t >> 6;
        const int rowBase = chunk * ROWS_PER_BLOCK;

        float s1 = 0.0f, s2 = 0.0f;
        #pragma unroll
        for (int k = 0; k < ROWS_PER_BLOCK / 4; ++k) {   // 8 coalesced loads
            const float v = y[(rowBase + rsub + 4 * k) * D_COLS + col];
            s1 += v;
            s2 += v * v;
        }
        s1s[t] = s1;
        s2s[t] = s2;
        __syncthreads();

        if (t < 64) {
            const float a1 = s1s[t] + s1s[t + 64] + s1s[t + 128] + s1s[t + 192];
            const float a2 = s2s[t] + s2s[t + 64] + s2s[t + 128] + s2s[t + 192];
            ws[chunk * 128 + t]      = a1;
            ws[chunk * 128 + 64 + t] = a2;
        }
        // Release by lane 0 of the SAME wave that issued the partial stores.
        if (t == 0)
            __hip_atomic_store(&flags[chunk], FLAG_MAGIC, __ATOMIC_RELEASE,
                               __HIP_MEMORY_SCOPE_AGENT);
        return;
    }

    // ---- dedicated consumer (block 0): polls from dispatch onward ----
    if (t < 64) {
        while (__hip_atomic_load(&flags[t], __ATOMIC_ACQUIRE,
                                 __HIP_MEMORY_SCOPE_AGENT) != FLAG_MAGIC) { }
        // reset for the next (deterministic) replay
        __hip_atomic_store(&flags[t], 0ULL, __ATOMIC_RELAXED,
                           __HIP_MEMORY_SCOPE_AGENT);
    }
    __syncthreads();

    // 8192 partial floats; thread t handles column t&63 for 16 of the 64
    // producers (group t>>6). Agent-scope loads bypass stale caches.
    const int col = t & 63;
    const int grp = t >> 6;
    float S1 = 0.0f, S2 = 0.0f;
    #pragma unroll
    for (int k = 0; k < 16; ++k) {
        const int bb = grp * 16 + k;
        S1 += __hip_atomic_load(&ws[bb * 128 + col], __ATOMIC_RELAXED,
                                __HIP_MEMORY_SCOPE_AGENT);
        S2 += __hip_atomic_load(&ws[bb * 128 + 64 + col], __ATOMIC_RELAXED,
                                __HIP_MEMORY_SCOPE_AGENT);
    }
    s1s[t] = S1;
    s2s[t] = S2;
    __syncthreads();

    if (t < 64) {
        const float T1 = s1s[t] + s1s[t + 64] + s1s[t + 128] + s1s[t + 192];
        const float T2 = s2s[t] + s2s[t + 64] + s2s[t + 128] + s2s[t + 192];
        const float invN = 1.0f / (float)N_ROWS;
        float v = T2 * invN - (T1 * invN) * (T1 * invN);
        #pragma unroll
        for (int off = 32; off > 0; off >>= 1)
            v += __shfl_down(v, off);
        if (t == 0) out[0] = v;
    }
}

extern "C" void kernel_launch(void* const* d_in, const int* in_sizes, int n_in,
                              void* d_out, int out_size, void* d_ws, size_t ws_size,
                              hipStream_t stream) {
    const float* y = (const float*)d_in[0];
    float* out = (float*)d_out;
    float* ws  = (float*)d_ws;   // needs NPROD*128*4 + NPROD*8 = 33280 B

    mi_fused<<<NPROD + 1, NTHR, 0, stream>>>(y, ws, out);
}